// Round 4
// baseline (350.575 us; speedup 1.0000x reference)
//
#include <hip/hip_runtime.h>

// Problem: B=8, C=512, H=W=64, NH=8, D=64, window 8x8 (Ws=64), N=4096.
// Token dim is window-permuted AT THE LAYERNORM (bit-swap n[8:6]<->n[5:3], involution):
// qn/kvn/Q/K/V/attn-out all live in permuted space (windows contiguous); un-permute
// happens only in gemm_out's final transposed store. V stored transposed (b,h,d,wpos).
//
// Round-4 gemm_qkv: faithful port of the validated 256^2 8-phase schedule (m201).
// r2/r3 post-mortem: monolithic per-kt phases (one 12-read burst + one 32-MFMA burst,
// waves lock-stepped) expose the whole LDS-read latency every kt regardless of barrier
// count or prefetch depth (115 us, MfmaUtil 18%). The 8-phase template alternates small
// {4-8 ds_read | 1 half-tile stage | barrier | 16 MFMA} phases with counted vmcnt(4)
// at even phases only (drain-to-0 only at the tail), BK=64 K-tiles, 2 LDS buffers.

typedef unsigned short u16;
typedef __bf16 bf16x8 __attribute__((ext_vector_type(8)));
typedef float f32x4 __attribute__((ext_vector_type(4)));
typedef u16 u16x8 __attribute__((ext_vector_type(8)));
typedef u16 u16x4 __attribute__((ext_vector_type(4)));

__device__ __forceinline__ u16 f2bf(float f) {
    __bf16 h = (__bf16)f;
    return __builtin_bit_cast(u16, h);
}
__device__ __forceinline__ float bf2f(u16 u) {
    return (float)__builtin_bit_cast(__bf16, u);
}
__device__ __forceinline__ f32x4 mfma16(bf16x8 a, bf16x8 b, f32x4 c) {
    return __builtin_amdgcn_mfma_f32_16x16x32_bf16(a, b, c, 0, 0, 0);
}
__device__ __forceinline__ void gl_lds16(const u16* g, u16* l) {
    __builtin_amdgcn_global_load_lds((const __attribute__((address_space(1))) void*)g,
                                     (__attribute__((address_space(3))) void*)l, 16, 0, 0);
}
// window permutation: n = hn[11:9] r[8:6] wn[5:3] cc[2:0] -> hn wn r cc  (involution)
__device__ __forceinline__ int swapb(int n) {
    return (n & 0xE07) | ((n & 0x1C0) >> 3) | ((n & 0x038) << 3);
}

// ---------------------------------------------------------------------------
// Setup: bf16 weights, RoPE table (4096 x 64 [sin,cos] interleaved), bias (8,64,64).
// ---------------------------------------------------------------------------
__global__ __launch_bounds__(256) void setup_kernel(
    const float* __restrict__ Wq, const float* __restrict__ Wk,
    const float* __restrict__ Wv, const float* __restrict__ Wo,
    const float* __restrict__ btab,
    u16* __restrict__ wq, u16* __restrict__ wk,
    u16* __restrict__ wv, u16* __restrict__ wo,
    float* __restrict__ rope, float* __restrict__ biasf)
{
    int idx = blockIdx.x * 256 + threadIdx.x;
    {
        int w = idx >> 18, e = idx & 262143;
        const float* src = (w == 0) ? Wq : (w == 1) ? Wk : (w == 2) ? Wv : Wo;
        u16* dst = (w == 0) ? wq : (w == 1) ? wk : (w == 2) ? wv : wo;
        dst[e] = f2bf(src[e]);
    }
    if (idx < 131072) {
        int n = idx >> 5, j = idx & 31;
        float inv = powf(10000.0f, -(float)j / 32.0f);
        float a = (float)n * inv;
        float s, c;
        sincosf(a, &s, &c);
        rope[n * 64 + 2 * j] = s;
        rope[n * 64 + 2 * j + 1] = c;
    }
    if (idx < 32768) {
        int q = idx & 63, pp = (idx >> 6) & 63, h = idx >> 12;
        int r1 = pp >> 3, c1 = pp & 7, r2 = q >> 3, c2 = q & 7;
        int ri = (r1 - r2 + 7) * 15 + (c1 - c2 + 7);
        biasf[idx] = btab[ri * 8 + h];
    }
}

// ---------------------------------------------------------------------------
// LayerNorm over C=512, NCHW -> (B,Nperm,C) bf16, float4-vectorized input.
// Block: 32 consecutive tokens. grid = 1024.
// ---------------------------------------------------------------------------
__global__ __launch_bounds__(256) void ln_kernel(
    const float* __restrict__ x, const float* __restrict__ g,
    const float* __restrict__ be, u16* __restrict__ out)
{
    __shared__ u16 sX[512 * 36];  // [c][token], stride 36 (8B-aligned u16x4 stores)
    __shared__ float sS[1024];
    __shared__ float sQ[1024];
    __shared__ float sMu[32], sInv[32];

    const int tid = threadIdx.x;
    const int b = blockIdx.x >> 7, grp = blockIdx.x & 127;
    const int nbase = grp << 5;
    const int t4 = tid & 7;   // token quad (4 tokens each)
    const int cg = tid >> 3;  // 32 channels per iteration

    const float* xp = x + ((size_t)b << 21) + nbase + (t4 << 2);
    float sm[4] = {0.f, 0.f, 0.f, 0.f}, sq2[4] = {0.f, 0.f, 0.f, 0.f};
#pragma unroll 4
    for (int it = 0; it < 16; it++) {
        int c = (it << 5) + cg;
        f32x4 v = *(const f32x4*)&xp[(size_t)c << 12];
        u16x4 h;
#pragma unroll
        for (int r = 0; r < 4; r++) {
            sm[r] += v[r];
            sq2[r] += v[r] * v[r];
            h[r] = f2bf(v[r]);
        }
        *(u16x4*)&sX[c * 36 + (t4 << 2)] = h;
    }
#pragma unroll
    for (int r = 0; r < 4; r++) {
        sS[tid * 4 + r] = sm[r];
        sQ[tid * 4 + r] = sq2[r];
    }
    __syncthreads();
    if (tid < 32) {  // token tid: t4v = tid>>2, r = tid&3
        int t4v = tid >> 2, r = tid & 3;
        float a = 0.f, q2 = 0.f;
#pragma unroll
        for (int c2 = 0; c2 < 32; c2++) {
            int i2 = ((c2 << 3) + t4v) * 4 + r;
            a += sS[i2];
            q2 += sQ[i2];
        }
        float mu = a * (1.f / 512.f);
        float var = q2 * (1.f / 512.f) - mu * mu;
        sMu[tid] = mu;
        sInv[tid] = rsqrtf(var + 1e-5f);
    }
    __syncthreads();

    const int t = tid >> 3;         // 0..31
    const int cs = (tid & 7) << 3;  // 0..56
    float mu = sMu[t], inv = sInv[t];
    int p = swapb(nbase + t);  // permuted row
    size_t orow = ((size_t)((b << 12) + p)) * 512;
#pragma unroll
    for (int it = 0; it < 8; it++) {
        int c0 = cs + (it << 6);
        f32x4 g0 = *(const f32x4*)&g[c0];
        f32x4 g1 = *(const f32x4*)&g[c0 + 4];
        f32x4 e0 = *(const f32x4*)&be[c0];
        f32x4 e1 = *(const f32x4*)&be[c0 + 4];
        u16x8 o;
#pragma unroll
        for (int k = 0; k < 8; k++) {
            float v = bf2f(sX[(c0 + k) * 36 + t]);
            float gg = (k < 4) ? g0[k] : g1[k - 4];
            float bb = (k < 4) ? e0[k] : e1[k - 4];
            o[k] = f2bf((v - mu) * inv * gg + bb);
        }
        *(u16x8*)&out[orow + c0] = o;
    }
}

// ---------------------------------------------------------------------------
// Fused Q/K/V projection, 256x256 tile, 8-phase schedule, BK=64, 8 waves (2Mx4N).
// grid 768: XCD-swizzled; kind (0=Q,1=K,2=V), n0 = 0/256, m0 = tile row.
// LDS 128KB, u16 offsets: AX=0, BX=16384, AY=32768, BY=49152; within a buffer,
// kk-half (32 cols) at kk*8192, then row*32 + chunk*8, chunk XOR-swizzled
// (chunk' = chunk ^ ((row>>1)&3)) via pre-swizzled global source (linear LDS dest).
// Iteration it: phases 1-4 compute K-tile 2it (bufX) staging K(2it+1)->bufY halves
// {Ak0,Bk0,Ak1,Bk1}; phases 5-8 compute K(2it+1) (bufY) staging K(2it+2)->bufX.
// vmcnt(4) at even-phase ends (each half landed one barrier before first read);
// drain vmcnt(0) only at it=3 phase 6. 16 MFMA per phase under setprio(1).
// Q/K epilogue applies RoPE (n = swapb(row)); V epilogue writes (b,h,d,wpos).
// ---------------------------------------------------------------------------
__global__ __launch_bounds__(512, 2) void gemm_qkv(
    const u16* __restrict__ qn, const u16* __restrict__ kvn,
    const u16* __restrict__ wq, const u16* __restrict__ wk, const u16* __restrict__ wv,
    const float* __restrict__ bq, const float* __restrict__ bk, const float* __restrict__ bv,
    const float* __restrict__ rope,
    u16* __restrict__ Qr, u16* __restrict__ Kr, u16* __restrict__ VT)
{
    __shared__ __align__(16) u16 smem[65536];  // 128 KB

    const int bid = blockIdx.x;
    const int swz = (bid & 7) * 96 + (bid >> 3);  // 768 % 8 == 0 -> bijective
    const int kind = swz >> 8;
    const int rem = swz & 255;
    const int n0 = (rem >> 7) << 8;   // 0 or 256
    const int m0 = (rem & 127) << 8;  // 0..32512

    const u16* Asrc = (kind == 0) ? qn : kvn;
    const u16* W = (kind == 0) ? wq : (kind == 1) ? wk : wv;
    const float* bias = (kind == 0) ? bq : (kind == 1) ? bk : bv;

    const int tid = threadIdx.x;
    const int lane = tid & 63, wid = tid >> 6;
    const int ln = lane & 15, lq = lane >> 4;
    const int wr = wid >> 2, wc = wid & 3;  // wave -> (2M x 4N) sub-tile

    // staging geometry: thread t covers rows (t>>2) and (t>>2)+128, chunk t&3 of a
    // 32-col half; global source chunk pre-swizzled: cc = (t&3) ^ ((t>>3)&3).
    const int rr = tid >> 2;
    const int cc = (tid & 3) ^ ((tid >> 3) & 3);
    const u16* aSt = Asrc + (size_t)(m0 + rr) * 512 + cc * 8;
    const u16* bSt = W + (size_t)(n0 + rr) * 512 + cc * 8;

    const int AX = 0, BX = 16384, AY = 32768, BY = 49152;

#define SB() __builtin_amdgcn_sched_barrier(0)
#define BARRIER() do { SB(); __builtin_amdgcn_s_barrier(); SB(); } while (0)
#define VM4() asm volatile("s_waitcnt vmcnt(4)" ::: "memory")
#define VM0() asm volatile("s_waitcnt vmcnt(0)" ::: "memory")
// stage one 16KB half-tile (2 x gl_lds/thread): kt = K-tile index (BK=64), kk = half
#define STAGE_A(base, kt, kk) do { \
        const u16* _g = aSt + (kt) * 64 + (kk) * 32; \
        gl_lds16(_g, &smem[(base) + (kk) * 8192 + wid * 512]); \
        gl_lds16(_g + 65536, &smem[(base) + (kk) * 8192 + 4096 + wid * 512]); \
    } while (0)
#define STAGE_B(base, kt, kk) do { \
        const u16* _g = bSt + (kt) * 64 + (kk) * 32; \
        gl_lds16(_g, &smem[(base) + (kk) * 8192 + wid * 512]); \
        gl_lds16(_g + 65536, &smem[(base) + (kk) * 8192 + 4096 + wid * 512]); \
    } while (0)

    const int swzc = lq ^ ((ln >> 1) & 3);  // read-side swizzled 16B chunk
    const int aOff = wr * 4096 + ln * 32 + swzc * 8;
    const int bOff = wc * 2048 + ln * 32 + swzc * 8;

#define LDA(base, kk, mh) do { \
        Af[0] = *(const bf16x8*)&smem[(base) + (kk) * 8192 + (mh) * 2048 + 0 * 512 + aOff]; \
        Af[1] = *(const bf16x8*)&smem[(base) + (kk) * 8192 + (mh) * 2048 + 1 * 512 + aOff]; \
        Af[2] = *(const bf16x8*)&smem[(base) + (kk) * 8192 + (mh) * 2048 + 2 * 512 + aOff]; \
        Af[3] = *(const bf16x8*)&smem[(base) + (kk) * 8192 + (mh) * 2048 + 3 * 512 + aOff]; \
    } while (0)
#define LDB(base, kk) do { \
        Bf[0] = *(const bf16x8*)&smem[(base) + (kk) * 8192 + 0 * 512 + bOff]; \
        Bf[1] = *(const bf16x8*)&smem[(base) + (kk) * 8192 + 1 * 512 + bOff]; \
        Bf[2] = *(const bf16x8*)&smem[(base) + (kk) * 8192 + 2 * 512 + bOff]; \
        Bf[3] = *(const bf16x8*)&smem[(base) + (kk) * 8192 + 3 * 512 + bOff]; \
    } while (0)
#define MMA(mh) do { \
        __builtin_amdgcn_s_setprio(1); \
        _Pragma("unroll") \
        for (int fi = 0; fi < 4; ++fi) \
            _Pragma("unroll") \
            for (int j = 0; j < 4; ++j) \
                acc[(mh) * 4 + fi][j] = mfma16(Af[fi], Bf[j], acc[(mh) * 4 + fi][j]); \
        __builtin_amdgcn_s_setprio(0); \
    } while (0)

    f32x4 acc[8][4] = {};

    // prologue: stage K-tile 0 halves in ledger order [Ak0, Bk0, Ak1, Bk1]
    STAGE_A(AX, 0, 0);
    STAGE_B(BX, 0, 0);
    STAGE_A(AX, 0, 1);
    STAGE_B(BX, 0, 1);
    VM4();      // Ak0 + Bk0 landed (own loads); barrier -> block-wide
    BARRIER();

#pragma unroll
    for (int it = 0; it < 4; ++it) {
        const bool last = (it == 3);
        bf16x8 Af[4], Bf[4];
        // ---- p1: X(kk0, mh0); stage Y_A k0 = K(2it+1)
        LDA(AX, 0, 0);
        LDB(BX, 0);
        STAGE_A(AY, 2 * it + 1, 0);
        BARRIER();
        MMA(0);
        BARRIER();
        // ---- p2: X(kk0, mh1); stage Y_B k0; gate
        LDA(AX, 0, 1);
        STAGE_B(BY, 2 * it + 1, 0);
        BARRIER();
        MMA(1);
        VM4();  // X k1 halves landed -> p3 safe
        BARRIER();
        // ---- p3: X(kk1, mh0); stage Y_A k1
        LDA(AX, 1, 0);
        LDB(BX, 1);
        STAGE_A(AY, 2 * it + 1, 1);
        BARRIER();
        MMA(0);
        BARRIER();
        // ---- p4: X(kk1, mh1); stage Y_B k1; gate
        LDA(AX, 1, 1);
        STAGE_B(BY, 2 * it + 1, 1);
        BARRIER();
        MMA(1);
        VM4();  // Y k0 halves landed -> p5 safe
        BARRIER();
        // ---- p5: Y(kk0, mh0); stage X_A k0 = K(2it+2)
        LDA(AY, 0, 0);
        LDB(BY, 0);
        if (!last) STAGE_A(AX, 2 * it + 2, 0);
        BARRIER();
        MMA(0);
        BARRIER();
        // ---- p6: Y(kk0, mh1); stage X_B k0; gate
        LDA(AY, 0, 1);
        if (!last) STAGE_B(BX, 2 * it + 2, 0);
        BARRIER();
        MMA(1);
        if (!last) {
            VM4();  // Y k1 halves landed -> p7 safe
        } else {
            VM0();  // tail: drain remaining Y k1 halves
        }
        BARRIER();
        // ---- p7: Y(kk1, mh0); stage X_A k1
        LDA(AY, 1, 0);
        LDB(BY, 1);
        if (!last) STAGE_A(AX, 2 * it + 2, 1);
        BARRIER();
        MMA(0);
        BARRIER();
        // ---- p8: Y(kk1, mh1); stage X_B k1; gate
        LDA(AY, 1, 1);
        if (!last) STAGE_B(BX, 2 * it + 2, 1);
        BARRIER();
        MMA(1);
        if (!last) VM4();  // next X k0 halves landed -> next p1 safe
        BARRIER();
    }

#undef SB
#undef BARRIER
#undef VM4
#undef VM0
#undef STAGE_A
#undef STAGE_B
#undef LDA
#undef LDB
#undef MMA

    // ------------------------- epilogue -------------------------
    float bj[4];
#pragma unroll
    for (int j = 0; j < 4; ++j) bj[j] = bias[n0 + wc * 64 + j * 16 + ln];

    u16* sU = smem;  // 64 x 264 u16 staging (33 KB), reused per group

    if (kind < 2) {
        u16* Out = (kind == 0) ? Qr : Kr;
#pragma unroll
        for (int g = 0; g < 4; ++g) {  // row-groups of 64 tokens
            __syncthreads();
            if (wr == (g >> 1)) {
                const int i0 = (g & 1) * 4;
#pragma unroll
                for (int di = 0; di < 4; ++di)
#pragma unroll
                    for (int j = 0; j < 4; ++j)
#pragma unroll
                        for (int r = 0; r < 4; ++r)
                            sU[(di * 16 + lq * 4 + r) * 264 + wc * 64 + j * 16 + ln] =
                                f2bf(acc[i0 + di][j][r] + bj[j]);
            }
            __syncthreads();
#pragma unroll
            for (int it = 0; it < 4; ++it) {
                int idx = it * 512 + tid;
                int row = idx >> 5;
                int cseg = (idx & 31) << 3;
                u16x8 v = *(const u16x8*)&sU[row * 264 + cseg];
                int t = m0 + g * 64 + row;  // permuted row id (incl. batch)
                int n = swapb(t & 4095);    // original token for RoPE
                float f[8];
#pragma unroll
                for (int k = 0; k < 8; k++) f[k] = bf2f(v[k]);
                {
                    int d0 = cseg & 63;
                    const float* rp = &rope[n * 64 + d0];
                    f32x4 r0 = *(const f32x4*)rp;
                    f32x4 r1 = *(const f32x4*)(rp + 4);
#pragma unroll
                    for (int pp = 0; pp < 4; pp++) {
                        float sn = (pp < 2) ? r0[2 * pp] : r1[2 * (pp - 2)];
                        float cs2 = (pp < 2) ? r0[2 * pp + 1] : r1[2 * (pp - 2) + 1];
                        float x0 = f[2 * pp], x1 = f[2 * pp + 1];
                        f[2 * pp] = x0 * cs2 - x1 * sn;
                        f[2 * pp + 1] = x0 * sn + x1 * cs2;
                    }
                }
                u16x8 o;
#pragma unroll
                for (int k = 0; k < 8; k++) o[k] = f2bf(f[k]);
                *(u16x8*)&Out[(size_t)t * 512 + n0 + cseg] = o;
            }
        }
    } else {
        const int wq0 = m0 & 4095;
        const int bb = m0 >> 12;
#pragma unroll
        for (int g = 0; g < 4; ++g) {  // channel-groups of 64
            __syncthreads();
            if (wc == g) {  // 2 waves (wr 0,1) write their full acc transposed
#pragma unroll
                for (int i = 0; i < 8; ++i)
#pragma unroll
                    for (int j = 0; j < 4; ++j) {
                        u16x4 pk;
#pragma unroll
                        for (int r = 0; r < 4; ++r) pk[r] = f2bf(acc[i][j][r] + bj[j]);
                        *(u16x4*)&sU[(j * 16 + ln) * 264 + wr * 128 + i * 16 + lq * 4] = pk;
                    }
            }
            __syncthreads();
#pragma unroll
            for (int it = 0; it < 4; ++it) {
                int idx = it * 512 + tid;
                int col = idx >> 5;          // channel within group
                int ch = (idx & 31) << 3;    // token chunk
                u16x8 v = *(const u16x8*)&sU[col * 264 + ch];
                int c = n0 + g * 64 + col;
                int hh = c >> 6, dd = c & 63;
                *(u16x8*)&VT[((size_t)((((bb << 3) + hh) << 6) + dd)) * 4096 + wq0 + ch] = v;
            }
        }
    }
}

// ---------------------------------------------------------------------------
// Output projection + bias + residual(qn, LDS-staged) + un-permute + (B,C,N) f32.
// grid (256,4).
// ---------------------------------------------------------------------------
__global__ __launch_bounds__(256) void gemm_out(
    const u16* __restrict__ A, const u16* __restrict__ Bw,
    const float* __restrict__ bias, const u16* __restrict__ qn,
    float* __restrict__ Out)
{
    __shared__ u16 sA[128 * 32];
    __shared__ u16 sB[128 * 32];
    __shared__ u16 sR[128 * 136];  // residual tile [token][c]

    const int m0 = blockIdx.x * 128;
    const int n0 = blockIdx.y * 128;
    const int tid = threadIdx.x;
    const int lane = tid & 63, wave = tid >> 6;
    const int ln = lane & 15, lq = lane >> 4;
    const int wm = wave & 1, wn = wave >> 1;

    const int srow = wave * 16 + (lane >> 2);
    const int sseg = (lane & 3) << 3;
    const u16* gA0 = A + (size_t)(m0 + srow) * 512 + sseg;
    const u16* gA1 = gA0 + (size_t)64 * 512;
    const u16* gB0 = Bw + (size_t)(n0 + srow) * 512 + sseg;
    const u16* gB1 = gB0 + (size_t)64 * 512;
    u16* lA0 = &sA[wave * 16 * 32];
    u16* lA1 = &sA[(64 + wave * 16) * 32];
    u16* lB0 = &sB[wave * 16 * 32];
    u16* lB1 = &sB[(64 + wave * 16) * 32];

    f32x4 acc[4][4] = {};

    for (int kt = 0; kt < 512; kt += 32) {
        gl_lds16(gA0 + kt, lA0);
        gl_lds16(gA1 + kt, lA1);
        gl_lds16(gB0 + kt, lB0);
        gl_lds16(gB1 + kt, lB1);
        __syncthreads();
        bf16x8 af[4], bfr[4];
#pragma unroll
        for (int i = 0; i < 4; i++)
            af[i] = *(const bf16x8*)&sA[(wm * 64 + i * 16 + ln) * 32 + lq * 8];
#pragma unroll
        for (int j = 0; j < 4; j++)
            bfr[j] = *(const bf16x8*)&sB[(wn * 64 + j * 16 + ln) * 32 + lq * 8];
#pragma unroll
        for (int i = 0; i < 4; i++)
#pragma unroll
            for (int j = 0; j < 4; j++)
                acc[i][j] = mfma16(af[i], bfr[j], acc[i][j]);
        __syncthreads();
    }

    // stage residual tile: coalesced u16x8 rows (qn is permuted like A)
#pragma unroll
    for (int it = 0; it < 8; it++) {
        int idx = it * 256 + tid;
        int row = idx >> 4, c8 = (idx & 15) << 3;
        *(u16x8*)&sR[row * 136 + c8] = *(const u16x8*)&qn[(size_t)(m0 + row) * 512 + n0 + c8];
    }
    __syncthreads();

    int cj[4];
    float bj[4];
#pragma unroll
    for (int j = 0; j < 4; j++) {
        cj[j] = n0 + wn * 64 + j * 16 + ln;
        bj[j] = bias[cj[j]];
    }
#pragma unroll
    for (int i = 0; i < 4; i++) {
        int t0 = m0 + wm * 64 + i * 16 + lq * 4;  // permuted row id
        int bb = t0 >> 12;
        int nb = swapb(t0 & 4095);                // original token; +r contiguous
        int lrow = wm * 64 + i * 16 + lq * 4;
#pragma unroll
        for (int j = 0; j < 4; j++) {
            int lcol = wn * 64 + j * 16 + ln;
            f32x4 v;
#pragma unroll
            for (int r = 0; r < 4; r++)
                v[r] = acc[i][j][r] + bj[j] + bf2f(sR[(lrow + r) * 136 + lcol]);
            *(f32x4*)&Out[((size_t)((bb << 9) + cj[j]) << 12) + nb] = v;
        }
    }
}

// ---------------------------------------------------------------------------
// Windowed attention: block = (b, window, head); all inputs window-contiguous.
// grid 4096: h = bid&7, w = (bid>>3)&63, b = bid>>9.
// ---------------------------------------------------------------------------
__global__ __launch_bounds__(256) void attn_kernel(
    const u16* __restrict__ Q, const u16* __restrict__ K, const u16* __restrict__ VT,
    const float* __restrict__ biasf, u16* __restrict__ Out)
{
    __shared__ u16 sQ[64 * 72];   // reused as output staging
    __shared__ u16 sK[64 * 72];
    __shared__ u16 sVT[64 * 72];  // [d][token]
    __shared__ u16 sP[4][16 * 72];

    const int tid = threadIdx.x;
    const int h = blockIdx.x & 7;
    const int w = (blockIdx.x >> 3) & 63;
    const int b = blockIdx.x >> 9;
    const int lane = tid & 63, wave = tid >> 6;
    const int ln = lane & 15, lq = lane >> 4;

    const size_t qrow0 = (size_t)(b << 12) + w * 64;
    const size_t vrow0 = ((size_t)(((b << 3) + h) << 6)) * 4096 + w * 64;

#pragma unroll
    for (int ii = 0; ii < 2; ii++) {
        int idx = ii * 256 + tid;
        int row = idx >> 3, ch = (idx & 7) << 3;
        size_t ga = (qrow0 + row) * 512 + h * 64 + ch;
        *(u16x8*)&sQ[row * 72 + ch] = *(const u16x8*)&Q[ga];
        *(u16x8*)&sK[row * 72 + ch] = *(const u16x8*)&K[ga];
        *(u16x8*)&sVT[row * 72 + ch] = *(const u16x8*)&VT[vrow0 + (size_t)row * 4096 + ch];
    }
    __syncthreads();

    f32x4 s[4] = {};
#pragma unroll
    for (int ks = 0; ks < 2; ks++) {
        bf16x8 a = *(const bf16x8*)&sQ[(wave * 16 + ln) * 72 + ks * 32 + lq * 8];
#pragma unroll
        for (int j = 0; j < 4; j++) {
            bf16x8 bb = *(const bf16x8*)&sK[(j * 16 + ln) * 72 + ks * 32 + lq * 8];
            s[j] = mfma16(a, bb, s[j]);
        }
    }

    float sv[4][4];
#pragma unroll
    for (int r = 0; r < 4; r++) {
        const float* bp = &biasf[((h * 64 + wave * 16 + lq * 4 + r) << 6) + ln];
#pragma unroll
        for (int j = 0; j < 4; j++) sv[r][j] = s[j][r] * 0.125f + bp[j * 16];
    }
#pragma unroll
    for (int r = 0; r < 4; r++) {
        float m = fmaxf(fmaxf(sv[r][0], sv[r][1]), fmaxf(sv[r][2], sv[r][3]));
        m = fmaxf(m, __shfl_xor(m, 1));
        m = fmaxf(m, __shfl_xor(m, 2));
        m = fmaxf(m, __shfl_xor(m, 4));
        m = fmaxf(m, __shfl_xor(m, 8));
        float sum = 0.f;
#pragma unroll
        for (int j = 0; j < 4; j++) {
            sv[r][j] = __expf(sv[r][j] - m);
            sum += sv[r][j];
        }
        sum += __shfl_xor(sum, 1);
        sum += __shfl_xor(sum, 2);
        sum += __shfl_xor(sum, 4);
        sum += __shfl_xor(sum, 8);
        float rinv = 1.f / sum;
#pragma unroll
        for (int j = 0; j < 4; j++)
            sP[wave][(lq * 4 + r) * 72 + j * 16 + ln] = f2bf(sv[r][j] * rinv);
    }
    // wave-private strip: no barrier needed

    f32x4 o[4] = {};
#pragma unroll
    for (int ks = 0; ks < 2; ks++) {
        bf16x8 a = *(const bf16x8*)&sP[wave][ln * 72 + ks * 32 + lq * 8];
#pragma unroll
        for (int jd = 0; jd < 4; jd++) {
            bf16x8 bb = *(const bf16x8*)&sVT[(jd * 16 + ln) * 72 + ks * 32 + lq * 8];
            o[jd] = mfma16(a, bb, o[jd]);
        }
    }

#pragma unroll
    for (int r = 0; r < 4; r++)
#pragma unroll
        for (int jd = 0; jd < 4; jd++)
            sQ[(wave * 16 + lq * 4 + r) * 72 + jd * 16 + ln] = f2bf(o[jd][r]);
    __syncthreads();
#pragma unroll
    for (int ii = 0; ii < 2; ii++) {
        int idx = ii * 256 + tid;
        int row = idx >> 3, ch = (idx & 7) << 3;
        *(u16x8*)&Out[(qrow0 + row) * 512 + h * 64 + ch] = *(const u16x8*)&sQ[row * 72 + ch];
    }
}

// ---------------------------------------------------------------------------
extern "C" void kernel_launch(void* const* d_in, const int* in_sizes, int n_in,
                              void* d_out, int out_size, void* d_ws, size_t ws_size,
                              hipStream_t stream)
{
    const float* q    = (const float*)d_in[0];
    const float* kv   = (const float*)d_in[1];
    const float* g_q  = (const float*)d_in[2];
    const float* b_q  = (const float*)d_in[3];
    const float* g_kv = (const float*)d_in[4];
    const float* b_kv = (const float*)d_in[5];
    const float* Wq   = (const float*)d_in[6];
    const float* bq   = (const float*)d_in[7];
    const float* Wk   = (const float*)d_in[8];
    const float* bk   = (const float*)d_in[9];
    const float* Wv   = (const float*)d_in[10];
    const float* bv   = (const float*)d_in[11];
    const float* Wo   = (const float*)d_in[12];
    const float* bo   = (const float*)d_in[13];
    const float* btab = (const float*)d_in[14];

    char* ws = (char*)d_ws;
    u16* qn      = (u16*)(ws);                 // 33,554,432 B  (permuted token order)
    u16* kvn     = (u16*)(ws + 33554432);      // 33,554,432 B  (reused as attn out)
    u16* VT      = (u16*)(ws + 67108864);      // 33,554,432 B  (b,h,d,wpos)
    float* rope  = (float*)(ws + 100663296);   // 1,048,576 B
    float* biasf = (float*)(ws + 101711872);   // 131,072 B
    u16* wq      = (u16*)(ws + 101842944);     // 4 x 524,288 B
    u16* wk      = (u16*)(ws + 102367232);
    u16* wv      = (u16*)(ws + 102891520);
    u16* wo      = (u16*)(ws + 103415808);
    u16* aout    = kvn;                        // safe: kvn consumed by QKV projection
    u16* Qr      = (u16*)d_out;                // d_out as scratch for Q/K (bf16)
    u16* Kr      = Qr + 16777216;

    setup_kernel<<<4096, 256, 0, stream>>>(Wq, Wk, Wv, Wo, btab, wq, wk, wv, wo, rope, biasf);
    ln_kernel<<<1024, 256, 0, stream>>>(q, g_q, b_q, qn);
    ln_kernel<<<1024, 256, 0, stream>>>(kv, g_kv, b_kv, kvn);
    gemm_qkv<<<768, 512, 0, stream>>>(qn, kvn, wq, wk, wv, bq, bk, bv, rope, Qr, Kr, VT);
    attn_kernel<<<4096, 256, 0, stream>>>(Qr, Kr, VT, biasf, aout);
    gemm_out<<<dim3(256, 4), 256, 0, stream>>>(aout, wo, bo, qn, (float*)d_out);
}

// Round 5
// 344.206 us; speedup vs baseline: 1.0185x; 1.0185x over previous
//
#include <hip/hip_runtime.h>

// Problem: B=8, C=512, H=W=64, NH=8, D=64, window 8x8 (Ws=64), N=4096.
// Token dim is window-permuted AT THE LAYERNORM (bit-swap n[8:6]<->n[5:3], involution):
// qn/kvn/Q/K/V/attn-out all live in permuted space (windows contiguous); un-permute
// happens only in gemm_out's final transposed store. V stored transposed (b,h,d,wpos).
//
// Round-5: (1) setup + both LayerNorms merged into one role-switched prep_kernel
// (removes 2 serialized launches; setup's VALU-heavy blocks overlap LN's BW-bound
// blocks). (2) gemm_out rebuilt on the round-4 8-phase 256^2 core (same M/N/K shape
// as gemm_qkv; main loop shared via macros), epilogue = LDS residual staging + bias
// + un-permute + f32 store; grid 256 = 1 block/CU. gemm_qkv unchanged (79.5us, 26%).

typedef unsigned short u16;
typedef __bf16 bf16x8 __attribute__((ext_vector_type(8)));
typedef float f32x4 __attribute__((ext_vector_type(4)));
typedef u16 u16x8 __attribute__((ext_vector_type(8)));
typedef u16 u16x4 __attribute__((ext_vector_type(4)));

__device__ __forceinline__ u16 f2bf(float f) {
    __bf16 h = (__bf16)f;
    return __builtin_bit_cast(u16, h);
}
__device__ __forceinline__ float bf2f(u16 u) {
    return (float)__builtin_bit_cast(__bf16, u);
}
__device__ __forceinline__ f32x4 mfma16(bf16x8 a, bf16x8 b, f32x4 c) {
    return __builtin_amdgcn_mfma_f32_16x16x32_bf16(a, b, c, 0, 0, 0);
}
__device__ __forceinline__ void gl_lds16(const u16* g, u16* l) {
    __builtin_amdgcn_global_load_lds((const __attribute__((address_space(1))) void*)g,
                                     (__attribute__((address_space(3))) void*)l, 16, 0, 0);
}
// window permutation: n = hn[11:9] r[8:6] wn[5:3] cc[2:0] -> hn wn r cc  (involution)
__device__ __forceinline__ int swapb(int n) {
    return (n & 0xE07) | ((n & 0x1C0) >> 3) | ((n & 0x038) << 3);
}

// ---------------------------------------------------------------------------
// prep_kernel: grid 6144 x 256.
//  blocks [0,1024):    LayerNorm q  -> qn   (permuted bf16)
//  blocks [1024,2048): LayerNorm kv -> kvn
//  blocks [2048,6144): setup: bf16 weights, RoPE table, bias table
// All roles independent; merged to overlap BW-bound LN with VALU-bound setup.
// ---------------------------------------------------------------------------
__global__ __launch_bounds__(256) void prep_kernel(
    const float* __restrict__ q, const float* __restrict__ kv,
    const float* __restrict__ g_q, const float* __restrict__ b_q,
    const float* __restrict__ g_kv, const float* __restrict__ b_kv,
    const float* __restrict__ Wq, const float* __restrict__ Wk,
    const float* __restrict__ Wv, const float* __restrict__ Wo,
    const float* __restrict__ btab,
    u16* __restrict__ qn, u16* __restrict__ kvn,
    u16* __restrict__ wq, u16* __restrict__ wk,
    u16* __restrict__ wv, u16* __restrict__ wo,
    float* __restrict__ rope, float* __restrict__ biasf)
{
    __shared__ u16 sX[512 * 36];  // [c][token], stride 36 (8B-aligned u16x4 stores)
    __shared__ float sS[1024];
    __shared__ float sQm[1024];
    __shared__ float sMu[32], sInv[32];

    const int bidx = blockIdx.x;
    const int tid = threadIdx.x;

    if (bidx >= 2048) {  // ---------------- setup role ----------------
        int idx = (bidx - 2048) * 256 + tid;
        {
            int w = idx >> 18, e = idx & 262143;
            const float* src = (w == 0) ? Wq : (w == 1) ? Wk : (w == 2) ? Wv : Wo;
            u16* dst = (w == 0) ? wq : (w == 1) ? wk : (w == 2) ? wv : wo;
            dst[e] = f2bf(src[e]);
        }
        if (idx < 131072) {
            int n = idx >> 5, j = idx & 31;
            float inv = powf(10000.0f, -(float)j / 32.0f);
            float a = (float)n * inv;
            float s, c;
            sincosf(a, &s, &c);
            rope[n * 64 + 2 * j] = s;
            rope[n * 64 + 2 * j + 1] = c;
        }
        if (idx < 32768) {
            int qq = idx & 63, pp = (idx >> 6) & 63, h = idx >> 12;
            int r1 = pp >> 3, c1 = pp & 7, r2 = qq >> 3, c2 = qq & 7;
            int ri = (r1 - r2 + 7) * 15 + (c1 - c2 + 7);
            biasf[idx] = btab[ri * 8 + h];
        }
        return;
    }

    // ---------------- LayerNorm role ----------------
    const float* x  = (bidx < 1024) ? q : kv;
    const float* g  = (bidx < 1024) ? g_q : g_kv;
    const float* be = (bidx < 1024) ? b_q : b_kv;
    u16* out = (bidx < 1024) ? qn : kvn;
    const int bid = bidx & 1023;

    const int b = bid >> 7, grp = bid & 127;
    const int nbase = grp << 5;
    const int t4 = tid & 7;   // token quad (4 tokens each)
    const int cg = tid >> 3;  // 32 channels per iteration

    const float* xp = x + ((size_t)b << 21) + nbase + (t4 << 2);
    float sm[4] = {0.f, 0.f, 0.f, 0.f}, sq2[4] = {0.f, 0.f, 0.f, 0.f};
#pragma unroll 4
    for (int it = 0; it < 16; it++) {
        int c = (it << 5) + cg;
        f32x4 v = *(const f32x4*)&xp[(size_t)c << 12];
        u16x4 h;
#pragma unroll
        for (int r = 0; r < 4; r++) {
            sm[r] += v[r];
            sq2[r] += v[r] * v[r];
            h[r] = f2bf(v[r]);
        }
        *(u16x4*)&sX[c * 36 + (t4 << 2)] = h;
    }
#pragma unroll
    for (int r = 0; r < 4; r++) {
        sS[tid * 4 + r] = sm[r];
        sQm[tid * 4 + r] = sq2[r];
    }
    __syncthreads();
    if (tid < 32) {  // token tid: t4v = tid>>2, r = tid&3
        int t4v = tid >> 2, r = tid & 3;
        float a = 0.f, q2 = 0.f;
#pragma unroll
        for (int c2 = 0; c2 < 32; c2++) {
            int i2 = ((c2 << 3) + t4v) * 4 + r;
            a += sS[i2];
            q2 += sQm[i2];
        }
        float mu = a * (1.f / 512.f);
        float var = q2 * (1.f / 512.f) - mu * mu;
        sMu[tid] = mu;
        sInv[tid] = rsqrtf(var + 1e-5f);
    }
    __syncthreads();

    const int t = tid >> 3;         // 0..31
    const int cs = (tid & 7) << 3;  // 0..56
    float mu = sMu[t], inv = sInv[t];
    int p = swapb(nbase + t);  // permuted row
    size_t orow = ((size_t)((b << 12) + p)) * 512;
#pragma unroll
    for (int it = 0; it < 8; it++) {
        int c0 = cs + (it << 6);
        f32x4 g0 = *(const f32x4*)&g[c0];
        f32x4 g1 = *(const f32x4*)&g[c0 + 4];
        f32x4 e0 = *(const f32x4*)&be[c0];
        f32x4 e1 = *(const f32x4*)&be[c0 + 4];
        u16x8 o;
#pragma unroll
        for (int k = 0; k < 8; k++) {
            float v = bf2f(sX[(c0 + k) * 36 + t]);
            float gg = (k < 4) ? g0[k] : g1[k - 4];
            float bb = (k < 4) ? e0[k] : e1[k - 4];
            o[k] = f2bf((v - mu) * inv * gg + bb);
        }
        *(u16x8*)&out[orow + c0] = o;
    }
}

// ---------------------------------------------------------------------------
// Shared 8-phase 256x256 / BK=64 / 8-wave main-loop machinery (round-4 verified).
// LDS 128KB, u16 offsets: AX=0, BX=16384, AY=32768, BY=49152; within a buffer,
// kk-half (32 cols) at kk*8192, row*32 + chunk*8, chunk XOR-swizzled
// (chunk' = chunk ^ ((row>>1)&3)) via pre-swizzled global source (linear LDS dest).
// vmcnt(4) at even-phase ends; drain vmcnt(0) only at it=3 phase 6.
// ---------------------------------------------------------------------------
#define SB() __builtin_amdgcn_sched_barrier(0)
#define BARRIER() do { SB(); __builtin_amdgcn_s_barrier(); SB(); } while (0)
#define VM4() asm volatile("s_waitcnt vmcnt(4)" ::: "memory")
#define VM0() asm volatile("s_waitcnt vmcnt(0)" ::: "memory")
#define STAGE_A(base, kt, kk) do { \
        const u16* _g = aSt + (kt) * 64 + (kk) * 32; \
        gl_lds16(_g, &smem[(base) + (kk) * 8192 + wid * 512]); \
        gl_lds16(_g + 65536, &smem[(base) + (kk) * 8192 + 4096 + wid * 512]); \
    } while (0)
#define STAGE_B(base, kt, kk) do { \
        const u16* _g = bSt + (kt) * 64 + (kk) * 32; \
        gl_lds16(_g, &smem[(base) + (kk) * 8192 + wid * 512]); \
        gl_lds16(_g + 65536, &smem[(base) + (kk) * 8192 + 4096 + wid * 512]); \
    } while (0)
#define LDA(base, kk, mh) do { \
        Af[0] = *(const bf16x8*)&smem[(base) + (kk) * 8192 + (mh) * 2048 + 0 * 512 + aOff]; \
        Af[1] = *(const bf16x8*)&smem[(base) + (kk) * 8192 + (mh) * 2048 + 1 * 512 + aOff]; \
        Af[2] = *(const bf16x8*)&smem[(base) + (kk) * 8192 + (mh) * 2048 + 2 * 512 + aOff]; \
        Af[3] = *(const bf16x8*)&smem[(base) + (kk) * 8192 + (mh) * 2048 + 3 * 512 + aOff]; \
    } while (0)
#define LDB(base, kk) do { \
        Bf[0] = *(const bf16x8*)&smem[(base) + (kk) * 8192 + 0 * 512 + bOff]; \
        Bf[1] = *(const bf16x8*)&smem[(base) + (kk) * 8192 + 1 * 512 + bOff]; \
        Bf[2] = *(const bf16x8*)&smem[(base) + (kk) * 8192 + 2 * 512 + bOff]; \
        Bf[3] = *(const bf16x8*)&smem[(base) + (kk) * 8192 + 3 * 512 + bOff]; \
    } while (0)
#define MMA(mh) do { \
        __builtin_amdgcn_s_setprio(1); \
        _Pragma("unroll") \
        for (int fi = 0; fi < 4; ++fi) \
            _Pragma("unroll") \
            for (int j = 0; j < 4; ++j) \
                acc[(mh) * 4 + fi][j] = mfma16(Af[fi], Bf[j], acc[(mh) * 4 + fi][j]); \
        __builtin_amdgcn_s_setprio(0); \
    } while (0)

#define MAIN_LOOP_8PHASE() \
    STAGE_A(AX, 0, 0); \
    STAGE_B(BX, 0, 0); \
    STAGE_A(AX, 0, 1); \
    STAGE_B(BX, 0, 1); \
    VM4(); \
    BARRIER(); \
    _Pragma("unroll") \
    for (int it = 0; it < 4; ++it) { \
        const bool last = (it == 3); \
        bf16x8 Af[4], Bf[4]; \
        LDA(AX, 0, 0); LDB(BX, 0); STAGE_A(AY, 2 * it + 1, 0); \
        BARRIER(); MMA(0); BARRIER(); \
        LDA(AX, 0, 1); STAGE_B(BY, 2 * it + 1, 0); \
        BARRIER(); MMA(1); VM4(); BARRIER(); \
        LDA(AX, 1, 0); LDB(BX, 1); STAGE_A(AY, 2 * it + 1, 1); \
        BARRIER(); MMA(0); BARRIER(); \
        LDA(AX, 1, 1); STAGE_B(BY, 2 * it + 1, 1); \
        BARRIER(); MMA(1); VM4(); BARRIER(); \
        LDA(AY, 0, 0); LDB(BY, 0); if (!last) STAGE_A(AX, 2 * it + 2, 0); \
        BARRIER(); MMA(0); BARRIER(); \
        LDA(AY, 0, 1); if (!last) STAGE_B(BX, 2 * it + 2, 0); \
        BARRIER(); MMA(1); \
        if (!last) { VM4(); } else { VM0(); } \
        BARRIER(); \
        LDA(AY, 1, 0); LDB(BY, 1); if (!last) STAGE_A(AX, 2 * it + 2, 1); \
        BARRIER(); MMA(0); BARRIER(); \
        LDA(AY, 1, 1); if (!last) STAGE_B(BX, 2 * it + 2, 1); \
        BARRIER(); MMA(1); if (!last) VM4(); BARRIER(); \
    }

// ---------------------------------------------------------------------------
// Fused Q/K/V projection, 8-phase core. grid 768: XCD-swizzled;
// kind (0=Q,1=K,2=V), n0 = 0/256, m0 = tile row.
// Q/K epilogue applies RoPE (n = swapb(row)); V epilogue writes (b,h,d,wpos).
// ---------------------------------------------------------------------------
__global__ __launch_bounds__(512, 2) void gemm_qkv(
    const u16* __restrict__ qn, const u16* __restrict__ kvn,
    const u16* __restrict__ wq, const u16* __restrict__ wk, const u16* __restrict__ wv,
    const float* __restrict__ bq, const float* __restrict__ bk, const float* __restrict__ bv,
    const float* __restrict__ rope,
    u16* __restrict__ Qr, u16* __restrict__ Kr, u16* __restrict__ VT)
{
    __shared__ __align__(16) u16 smem[65536];  // 128 KB

    const int bid = blockIdx.x;
    const int swz = (bid & 7) * 96 + (bid >> 3);  // 768 % 8 == 0 -> bijective
    const int kind = swz >> 8;
    const int rem = swz & 255;
    const int n0 = (rem >> 7) << 8;   // 0 or 256
    const int m0 = (rem & 127) << 8;  // 0..32512

    const u16* Asrc = (kind == 0) ? qn : kvn;
    const u16* W = (kind == 0) ? wq : (kind == 1) ? wk : wv;
    const float* bias = (kind == 0) ? bq : (kind == 1) ? bk : bv;

    const int tid = threadIdx.x;
    const int lane = tid & 63, wid = tid >> 6;
    const int ln = lane & 15, lq = lane >> 4;
    const int wr = wid >> 2, wc = wid & 3;  // wave -> (2M x 4N) sub-tile

    const int rr = tid >> 2;
    const int cc = (tid & 3) ^ ((tid >> 3) & 3);
    const u16* aSt = Asrc + (size_t)(m0 + rr) * 512 + cc * 8;
    const u16* bSt = W + (size_t)(n0 + rr) * 512 + cc * 8;

    const int AX = 0, BX = 16384, AY = 32768, BY = 49152;
    const int swzc = lq ^ ((ln >> 1) & 3);
    const int aOff = wr * 4096 + ln * 32 + swzc * 8;
    const int bOff = wc * 2048 + ln * 32 + swzc * 8;

    f32x4 acc[8][4] = {};

    MAIN_LOOP_8PHASE();

    // ------------------------- epilogue -------------------------
    float bj[4];
#pragma unroll
    for (int j = 0; j < 4; ++j) bj[j] = bias[n0 + wc * 64 + j * 16 + ln];

    u16* sU = smem;  // 64 x 264 u16 staging (33 KB), reused per group

    if (kind < 2) {
        u16* Out = (kind == 0) ? Qr : Kr;
#pragma unroll
        for (int g = 0; g < 4; ++g) {  // row-groups of 64 tokens
            __syncthreads();
            if (wr == (g >> 1)) {
                const int i0 = (g & 1) * 4;
#pragma unroll
                for (int di = 0; di < 4; ++di)
#pragma unroll
                    for (int j = 0; j < 4; ++j)
#pragma unroll
                        for (int r = 0; r < 4; ++r)
                            sU[(di * 16 + lq * 4 + r) * 264 + wc * 64 + j * 16 + ln] =
                                f2bf(acc[i0 + di][j][r] + bj[j]);
            }
            __syncthreads();
#pragma unroll
            for (int it = 0; it < 4; ++it) {
                int idx = it * 512 + tid;
                int row = idx >> 5;
                int cseg = (idx & 31) << 3;
                u16x8 v = *(const u16x8*)&sU[row * 264 + cseg];
                int t = m0 + g * 64 + row;  // permuted row id (incl. batch)
                int n = swapb(t & 4095);    // original token for RoPE
                float f[8];
#pragma unroll
                for (int k = 0; k < 8; k++) f[k] = bf2f(v[k]);
                {
                    int d0 = cseg & 63;
                    const float* rp = &rope[n * 64 + d0];
                    f32x4 r0 = *(const f32x4*)rp;
                    f32x4 r1 = *(const f32x4*)(rp + 4);
#pragma unroll
                    for (int pp = 0; pp < 4; pp++) {
                        float sn = (pp < 2) ? r0[2 * pp] : r1[2 * (pp - 2)];
                        float cs2 = (pp < 2) ? r0[2 * pp + 1] : r1[2 * (pp - 2) + 1];
                        float x0 = f[2 * pp], x1 = f[2 * pp + 1];
                        f[2 * pp] = x0 * cs2 - x1 * sn;
                        f[2 * pp + 1] = x0 * sn + x1 * cs2;
                    }
                }
                u16x8 o;
#pragma unroll
                for (int k = 0; k < 8; k++) o[k] = f2bf(f[k]);
                *(u16x8*)&Out[(size_t)t * 512 + n0 + cseg] = o;
            }
        }
    } else {
        const int wq0 = m0 & 4095;
        const int bb = m0 >> 12;
#pragma unroll
        for (int g = 0; g < 4; ++g) {  // channel-groups of 64
            __syncthreads();
            if (wc == g) {  // 2 waves (wr 0,1) write their full acc transposed
#pragma unroll
                for (int i = 0; i < 8; ++i)
#pragma unroll
                    for (int j = 0; j < 4; ++j) {
                        u16x4 pk;
#pragma unroll
                        for (int r = 0; r < 4; ++r) pk[r] = f2bf(acc[i][j][r] + bj[j]);
                        *(u16x4*)&sU[(j * 16 + ln) * 264 + wr * 128 + i * 16 + lq * 4] = pk;
                    }
            }
            __syncthreads();
#pragma unroll
            for (int it = 0; it < 4; ++it) {
                int idx = it * 512 + tid;
                int col = idx >> 5;          // channel within group
                int ch = (idx & 31) << 3;    // token chunk
                u16x8 v = *(const u16x8*)&sU[col * 264 + ch];
                int c = n0 + g * 64 + col;
                int hh = c >> 6, dd = c & 63;
                *(u16x8*)&VT[((size_t)((((bb << 3) + hh) << 6) + dd)) * 4096 + wq0 + ch] = v;
            }
        }
    }
}

// ---------------------------------------------------------------------------
// Output projection, 8-phase 256^2 core (same M/N/K as gemm_qkv). grid 256
// (1 block/CU), XCD-swizzled. Epilogue: bias + residual(qn, LDS-staged per
// 64-row group) + un-permute + (B,C,N) f32 store.
// ---------------------------------------------------------------------------
__global__ __launch_bounds__(512, 2) void gemm_out(
    const u16* __restrict__ A, const u16* __restrict__ Bw,
    const float* __restrict__ bias, const u16* __restrict__ qn,
    float* __restrict__ Out)
{
    __shared__ __align__(16) u16 smem[65536];  // 128 KB

    const int bid = blockIdx.x;
    const int swz = (bid & 7) * 32 + (bid >> 3);  // 256 % 8 == 0 -> bijective
    const int n0 = (swz >> 7) << 8;   // 0 or 256
    const int m0 = (swz & 127) << 8;  // 0..32512

    const int tid = threadIdx.x;
    const int lane = tid & 63, wid = tid >> 6;
    const int ln = lane & 15, lq = lane >> 4;
    const int wr = wid >> 2, wc = wid & 3;

    const int rr = tid >> 2;
    const int cc = (tid & 3) ^ ((tid >> 3) & 3);
    const u16* aSt = A + (size_t)(m0 + rr) * 512 + cc * 8;
    const u16* bSt = Bw + (size_t)(n0 + rr) * 512 + cc * 8;

    const int AX = 0, BX = 16384, AY = 32768, BY = 49152;
    const int swzc = lq ^ ((ln >> 1) & 3);
    const int aOff = wr * 4096 + ln * 32 + swzc * 8;
    const int bOff = wc * 2048 + ln * 32 + swzc * 8;

    f32x4 acc[8][4] = {};

    MAIN_LOOP_8PHASE();

    // ------------------------- epilogue -------------------------
    float bj[4];
#pragma unroll
    for (int j = 0; j < 4; ++j) bj[j] = bias[n0 + wc * 64 + j * 16 + ln];

    u16* sR = smem;  // 64 x 264 residual staging per 64-row group
#pragma unroll
    for (int g = 0; g < 4; ++g) {
        __syncthreads();
        // stage residual rows [m0+g*64, +64), cols [n0, n0+256), coalesced u16x8
#pragma unroll
        for (int it = 0; it < 4; ++it) {
            int idx = it * 512 + tid;
            int row = idx >> 5, c8 = (idx & 31) << 3;
            *(u16x8*)&sR[row * 264 + c8] =
                *(const u16x8*)&qn[(size_t)(m0 + g * 64 + row) * 512 + n0 + c8];
        }
        __syncthreads();
        if (wr == (g >> 1)) {
            const int i0 = (g & 1) * 4;
#pragma unroll
            for (int di = 0; di < 4; ++di) {
                int t0 = m0 + g * 64 + di * 16 + lq * 4;  // permuted row id
                int bb = t0 >> 12;
                int nb = swapb(t0 & 4095);                // original token; +r contiguous
                int lr = di * 16 + lq * 4;                // row within group
#pragma unroll
                for (int j = 0; j < 4; ++j) {
                    int c = wc * 64 + j * 16 + ln;        // col within N-tile
                    f32x4 v;
#pragma unroll
                    for (int r = 0; r < 4; ++r)
                        v[r] = acc[i0 + di][j][r] + bj[j] + bf2f(sR[(lr + r) * 264 + c]);
                    *(f32x4*)&Out[((size_t)((bb << 9) + n0 + c) << 12) + nb] = v;
                }
            }
        }
    }
}

#undef SB
#undef BARRIER
#undef VM4
#undef VM0
#undef STAGE_A
#undef STAGE_B
#undef LDA
#undef LDB
#undef MMA
#undef MAIN_LOOP_8PHASE

// ---------------------------------------------------------------------------
// Windowed attention: block = (b, window, head); all inputs window-contiguous.
// grid 4096: h = bid&7, w = (bid>>3)&63, b = bid>>9.
// ---------------------------------------------------------------------------
__global__ __launch_bounds__(256) void attn_kernel(
    const u16* __restrict__ Q, const u16* __restrict__ K, const u16* __restrict__ VT,
    const float* __restrict__ biasf, u16* __restrict__ Out)
{
    __shared__ u16 sQ[64 * 72];   // reused as output staging
    __shared__ u16 sK[64 * 72];
    __shared__ u16 sVT[64 * 72];  // [d][token]
    __shared__ u16 sP[4][16 * 72];

    const int tid = threadIdx.x;
    const int h = blockIdx.x & 7;
    const int w = (blockIdx.x >> 3) & 63;
    const int b = blockIdx.x >> 9;
    const int lane = tid & 63, wave = tid >> 6;
    const int ln = lane & 15, lq = lane >> 4;

    const size_t qrow0 = (size_t)(b << 12) + w * 64;
    const size_t vrow0 = ((size_t)(((b << 3) + h) << 6)) * 4096 + w * 64;

#pragma unroll
    for (int ii = 0; ii < 2; ii++) {
        int idx = ii * 256 + tid;
        int row = idx >> 3, ch = (idx & 7) << 3;
        size_t ga = (qrow0 + row) * 512 + h * 64 + ch;
        *(u16x8*)&sQ[row * 72 + ch] = *(const u16x8*)&Q[ga];
        *(u16x8*)&sK[row * 72 + ch] = *(const u16x8*)&K[ga];
        *(u16x8*)&sVT[row * 72 + ch] = *(const u16x8*)&VT[vrow0 + (size_t)row * 4096 + ch];
    }
    __syncthreads();

    f32x4 s[4] = {};
#pragma unroll
    for (int ks = 0; ks < 2; ks++) {
        bf16x8 a = *(const bf16x8*)&sQ[(wave * 16 + ln) * 72 + ks * 32 + lq * 8];
#pragma unroll
        for (int j = 0; j < 4; j++) {
            bf16x8 bb = *(const bf16x8*)&sK[(j * 16 + ln) * 72 + ks * 32 + lq * 8];
            s[j] = mfma16(a, bb, s[j]);
        }
    }

    float sv[4][4];
#pragma unroll
    for (int r = 0; r < 4; r++) {
        const float* bp = &biasf[((h * 64 + wave * 16 + lq * 4 + r) << 6) + ln];
#pragma unroll
        for (int j = 0; j < 4; j++) sv[r][j] = s[j][r] * 0.125f + bp[j * 16];
    }
#pragma unroll
    for (int r = 0; r < 4; r++) {
        float m = fmaxf(fmaxf(sv[r][0], sv[r][1]), fmaxf(sv[r][2], sv[r][3]));
        m = fmaxf(m, __shfl_xor(m, 1));
        m = fmaxf(m, __shfl_xor(m, 2));
        m = fmaxf(m, __shfl_xor(m, 4));
        m = fmaxf(m, __shfl_xor(m, 8));
        float sum = 0.f;
#pragma unroll
        for (int j = 0; j < 4; j++) {
            sv[r][j] = __expf(sv[r][j] - m);
            sum += sv[r][j];
        }
        sum += __shfl_xor(sum, 1);
        sum += __shfl_xor(sum, 2);
        sum += __shfl_xor(sum, 4);
        sum += __shfl_xor(sum, 8);
        float rinv = 1.f / sum;
#pragma unroll
        for (int j = 0; j < 4; j++)
            sP[wave][(lq * 4 + r) * 72 + j * 16 + ln] = f2bf(sv[r][j] * rinv);
    }
    // wave-private strip: no barrier needed

    f32x4 o[4] = {};
#pragma unroll
    for (int ks = 0; ks < 2; ks++) {
        bf16x8 a = *(const bf16x8*)&sP[wave][ln * 72 + ks * 32 + lq * 8];
#pragma unroll
        for (int jd = 0; jd < 4; jd++) {
            bf16x8 bb = *(const bf16x8*)&sVT[(jd * 16 + ln) * 72 + ks * 32 + lq * 8];
            o[jd] = mfma16(a, bb, o[jd]);
        }
    }

#pragma unroll
    for (int r = 0; r < 4; r++)
#pragma unroll
        for (int jd = 0; jd < 4; jd++)
            sQ[(wave * 16 + lq * 4 + r) * 72 + jd * 16 + ln] = f2bf(o[jd][r]);
    __syncthreads();
#pragma unroll
    for (int ii = 0; ii < 2; ii++) {
        int idx = ii * 256 + tid;
        int row = idx >> 3, ch = (idx & 7) << 3;
        *(u16x8*)&Out[(qrow0 + row) * 512 + h * 64 + ch] = *(const u16x8*)&sQ[row * 72 + ch];
    }
}

// ---------------------------------------------------------------------------
extern "C" void kernel_launch(void* const* d_in, const int* in_sizes, int n_in,
                              void* d_out, int out_size, void* d_ws, size_t ws_size,
                              hipStream_t stream)
{
    const float* q    = (const float*)d_in[0];
    const float* kv   = (const float*)d_in[1];
    const float* g_q  = (const float*)d_in[2];
    const float* b_q  = (const float*)d_in[3];
    const float* g_kv = (const float*)d_in[4];
    const float* b_kv = (const float*)d_in[5];
    const float* Wq   = (const float*)d_in[6];
    const float* bq   = (const float*)d_in[7];
    const float* Wk   = (const float*)d_in[8];
    const float* bk   = (const float*)d_in[9];
    const float* Wv   = (const float*)d_in[10];
    const float* bv   = (const float*)d_in[11];
    const float* Wo   = (const float*)d_in[12];
    const float* bo   = (const float*)d_in[13];
    const float* btab = (const float*)d_in[14];

    char* ws = (char*)d_ws;
    u16* qn      = (u16*)(ws);                 // 33,554,432 B  (permuted token order)
    u16* kvn     = (u16*)(ws + 33554432);      // 33,554,432 B  (reused as attn out)
    u16* VT      = (u16*)(ws + 67108864);      // 33,554,432 B  (b,h,d,wpos)
    float* rope  = (float*)(ws + 100663296);   // 1,048,576 B
    float* biasf = (float*)(ws + 101711872);   // 131,072 B
    u16* wq      = (u16*)(ws + 101842944);     // 4 x 524,288 B
    u16* wk      = (u16*)(ws + 102367232);
    u16* wv      = (u16*)(ws + 102891520);
    u16* wo      = (u16*)(ws + 103415808);
    u16* aout    = kvn;                        // safe: kvn consumed by QKV projection
    u16* Qr      = (u16*)d_out;                // d_out as scratch for Q/K (bf16)
    u16* Kr      = Qr + 16777216;

    prep_kernel<<<6144, 256, 0, stream>>>(q, kv, g_q, b_q, g_kv, b_kv,
                                          Wq, Wk, Wv, Wo, btab,
                                          qn, kvn, wq, wk, wv, wo, rope, biasf);
    gemm_qkv<<<768, 512, 0, stream>>>(qn, kvn, wq, wk, wv, bq, bk, bv, rope, Qr, Kr, VT);
    attn_kernel<<<4096, 256, 0, stream>>>(Qr, Kr, VT, biasf, aout);
    gemm_out<<<256, 512, 0, stream>>>(aout, wo, bo, qn, (float*)d_out);
}